// Round 1
// baseline (379.143 us; speedup 1.0000x reference)
//
#include <hip/hip_runtime.h>
#include <stdint.h>

#define T_TOK 8192
#define HD 1024
#define NE 16
#define NET 17
#define FD 512
#define CAP 8320
#define MAXRB 208

typedef unsigned int uint;
typedef unsigned short ushort;
typedef __attribute__((ext_vector_type(8))) __bf16 bf16x8;
typedef __attribute__((ext_vector_type(4))) float f32x4;
typedef __attribute__((ext_vector_type(8))) ushort u16x8;

// ws layout (bytes)
#define OFF_XBF   0ull
#define OFF_WUPT  16777216ull
#define OFF_WDT   52428800ull
#define OFF_ACT   70254592ull
#define OFF_EIDX  97517568ull
#define OFF_EW    97583104ull
#define OFF_TOK   97648640ull
#define OFF_WGT   98214400ull
#define OFF_META  98780160ull
#define WS_NEEDED (OFF_META + 4096ull)

__device__ __forceinline__ ushort f2bf(float f) {
    uint u = __float_as_uint(f);
    u += 0x7FFFu + ((u >> 16) & 1u);
    return (ushort)(u >> 16);
}

__device__ __forceinline__ void gload16(const void* g, void* l) {
    __builtin_amdgcn_global_load_lds(
        (const __attribute__((address_space(1))) void*)g,
        (__attribute__((address_space(3))) void*)l, 16, 0, 0);
}

// ---------------- conversions ----------------
__global__ void k_convert_x(const float* __restrict__ x, ushort* __restrict__ xb) {
    int i = (blockIdx.x * 256 + threadIdx.x) * 8;
    float4 a = *(const float4*)(x + i);
    float4 b = *(const float4*)(x + i + 4);
    u16x8 v;
    v[0] = f2bf(a.x); v[1] = f2bf(a.y); v[2] = f2bf(a.z); v[3] = f2bf(a.w);
    v[4] = f2bf(b.x); v[5] = f2bf(b.y); v[6] = f2bf(b.z); v[7] = f2bf(b.w);
    *(u16x8*)(xb + i) = v;
}

// W_up [E][H][2F] fp32 (+ shared [H][2F]) -> wupT [17][2F][H] bf16
__global__ void k_transpose_up(const float* __restrict__ Wup,
                               const float* __restrict__ Wsup,
                               ushort* __restrict__ dst) {
    int e = blockIdx.z;
    const float* src = (e < 16) ? (Wup + (size_t)e * HD * (2 * FD)) : Wsup;
    int h0 = blockIdx.y * 32, n0 = blockIdx.x * 32;
    __shared__ float tile[32][33];
    int tx = threadIdx.x, ty = threadIdx.y;
#pragma unroll
    for (int i = 0; i < 4; i++) {
        int r = ty + i * 8;
        tile[r][tx] = src[(size_t)(h0 + r) * (2 * FD) + n0 + tx];
    }
    __syncthreads();
#pragma unroll
    for (int i = 0; i < 4; i++) {
        int r = ty + i * 8;
        dst[(size_t)e * 1024 * 1024 + (size_t)(n0 + r) * 1024 + h0 + tx] = f2bf(tile[tx][r]);
    }
}

// W_down [E][F][H] fp32 (+ shared [F][H]) -> wdT [17][H][F] bf16
__global__ void k_transpose_dn(const float* __restrict__ Wdn,
                               const float* __restrict__ Wsdn,
                               ushort* __restrict__ dst) {
    int e = blockIdx.z;
    const float* src = (e < 16) ? (Wdn + (size_t)e * FD * HD) : Wsdn;
    int f0 = blockIdx.y * 32, h0 = blockIdx.x * 32;
    __shared__ float tile[32][33];
    int tx = threadIdx.x, ty = threadIdx.y;
#pragma unroll
    for (int i = 0; i < 4; i++) {
        int r = ty + i * 8;
        tile[r][tx] = src[(size_t)(f0 + r) * HD + h0 + tx];
    }
    __syncthreads();
#pragma unroll
    for (int i = 0; i < 4; i++) {
        int r = ty + i * 8;
        dst[(size_t)e * 1024 * 512 + (size_t)(h0 + r) * 512 + f0 + tx] = f2bf(tile[tx][r]);
    }
}

// ---------------- router ----------------
__global__ __launch_bounds__(256) void k_router(const float* __restrict__ x,
                                                const float* __restrict__ Wr,
                                                float* __restrict__ probs,
                                                int2* __restrict__ eidx,
                                                float2* __restrict__ ew) {
    int t = blockIdx.x;
    __shared__ float xs[HD];
    __shared__ float part[256];
    __shared__ float pl[NE];
    int tid = threadIdx.x;
    *(float4*)(xs + tid * 4) = *(const float4*)(x + (size_t)t * HD + tid * 4);
    __syncthreads();
    int e = tid & 15, g = tid >> 4;
    float s = 0.f;
#pragma unroll 8
    for (int h = g * 64; h < g * 64 + 64; ++h) s += xs[h] * Wr[h * NE + e];
    part[tid] = s;
    __syncthreads();
    if (tid < NE) {
        float l = 0.f;
#pragma unroll
        for (int gg = 0; gg < 16; ++gg) l += part[gg * 16 + tid];
        pl[tid] = l;
    }
    __syncthreads();
    if (tid == 0) {
        float mx = pl[0];
#pragma unroll
        for (int i = 1; i < NE; ++i) mx = fmaxf(mx, pl[i]);
        float p[NE];
        float sum = 0.f;
#pragma unroll
        for (int i = 0; i < NE; ++i) { p[i] = __expf(pl[i] - mx); sum += p[i]; }
        float inv = 1.f / sum;
        float m1 = -1.f; int i1 = 0;
#pragma unroll
        for (int i = 0; i < NE; ++i) {
            p[i] *= inv;
            probs[(size_t)t * NE + i] = p[i];
            if (p[i] > m1) { m1 = p[i]; i1 = i; }
        }
        float m2 = -1.f; int i2 = 0;
#pragma unroll
        for (int i = 0; i < NE; ++i) if (i != i1 && p[i] > m2) { m2 = p[i]; i2 = i; }
        float inv2 = 1.f / (m1 + m2 + 1e-9f);
        eidx[t] = make_int2(i1, i2);
        ew[t] = make_float2(m1 * inv2, m2 * inv2);
    }
}

// ---------------- bucketing ----------------
__global__ void k_assign(const int2* __restrict__ eidx, const float2* __restrict__ ew,
                         int* __restrict__ meta, int* __restrict__ tok,
                         float* __restrict__ wgt) {
    int t = blockIdx.x * 256 + threadIdx.x;
    int2 e = eidx[t];
    float2 w = ew[t];
    int p0 = atomicAdd(&meta[e.x], 1);
    tok[e.x * CAP + p0] = t; wgt[e.x * CAP + p0] = w.x;
    int p1 = atomicAdd(&meta[e.y], 1);
    tok[e.y * CAP + p1] = t; wgt[e.y * CAP + p1] = w.y;
    tok[16 * CAP + t] = t; wgt[16 * CAP + t] = 1.f;   // shared expert: identity list
    if (t == 0) meta[16] = T_TOK;
}

// meta: [0..16]=cnt, [17]=nRB, [32..]=rbE, [288..]=rbLoc, [544..]=rbActRow
__global__ void k_finalize(int* __restrict__ meta, int* __restrict__ tok,
                           float* __restrict__ wgt) {
    __shared__ int sN[NET], sPad[NET];
    int tid = threadIdx.x;
    if (tid == 0) {
        int idx = 0, aoff = 0;
        for (int e = 0; e < NET; e++) {
            int n = meta[e];
            int padded = (n + 127) & ~127;
            sN[e] = n; sPad[e] = padded;
            for (int i = 0; i < padded; i += 128) {
                meta[32 + idx] = e; meta[288 + idx] = i; meta[544 + idx] = aoff + i; idx++;
            }
            aoff += padded;
        }
        meta[17] = idx;
    }
    __syncthreads();
    for (int e = 0; e < NET; e++)
        for (int i = sN[e] + tid; i < sPad[e]; i += 256) {
            tok[e * CAP + i] = 0; wgt[e * CAP + i] = 0.f;
        }
}

// ---------------- grouped up-GEMM + SiLU (gate,up paired) ----------------
// tile: 128 rows x (128 gate + 128 up cols) ; BK=64 ; K=1024 ; 4 waves of 64x64(+64x64)
__global__ __launch_bounds__(256, 2) void k_up(const ushort* __restrict__ xb,
                                               const ushort* __restrict__ wupT,
                                               ushort* __restrict__ act,
                                               const int* __restrict__ tok,
                                               const int* __restrict__ meta) {
    int rb = blockIdx.y;
    if (rb >= meta[17]) return;
    __shared__ char smem[49152];  // A 16K | Bg 16K | Bu 16K ; epilogue reuses 32K
    int e = meta[32 + rb], rloc = meta[288 + rb], arow = meta[544 + rb];
    int cb = blockIdx.x;
    int tid = threadIdx.x, lane = tid & 63, wave = tid >> 6;

    // staging: thread stages LDS bytes [tid*16, +16) of each 4KB issue
    int srow = tid >> 3;              // row within 32-row issue
    int kb = (tid & 7) * 16;
    int swz = kb ^ ((srow & 7) << 4);
    const int listBase = e * CAP + rloc;
    int tokr[4];
#pragma unroll
    for (int i = 0; i < 4; i++) tokr[i] = tok[listBase + i * 32 + srow];
    const char* xbase = (const char*)xb;
    const char* wb = (const char*)wupT + (size_t)e * 1024 * 2048;
    int ng = cb * 128 + srow;

    int wr = wave >> 1, wc = wave & 1;
    int lr = lane & 15, lk = lane >> 4;
    int aBase = (wr * 64 + lr) * 128;
    int bBase = (wc * 64 + lr) * 128;
    int kpart[2];
#pragma unroll
    for (int kk = 0; kk < 2; kk++) kpart[kk] = (kk * 64 + lk * 16) ^ ((lr & 7) << 4);

    f32x4 accg[4][4], accu[4][4];
#pragma unroll
    for (int m = 0; m < 4; m++)
#pragma unroll
        for (int n = 0; n < 4; n++) {
            accg[m][n] = (f32x4){0.f, 0.f, 0.f, 0.f};
            accu[m][n] = (f32x4){0.f, 0.f, 0.f, 0.f};
        }

    char* As = smem;
    for (int kt = 0; kt < 16; ++kt) {
        __syncthreads();
        int kB = kt * 128;
#pragma unroll
        for (int i = 0; i < 4; i++)
            gload16(xbase + (size_t)tokr[i] * 2048 + kB + swz, As + i * 4096 + wave * 1024);
#pragma unroll
        for (int i = 0; i < 4; i++)
            gload16(wb + (size_t)(ng + i * 32) * 2048 + kB + swz, As + 16384 + i * 4096 + wave * 1024);
#pragma unroll
        for (int i = 0; i < 4; i++)
            gload16(wb + (size_t)(ng + 512 + i * 32) * 2048 + kB + swz, As + 32768 + i * 4096 + wave * 1024);
        asm volatile("s_waitcnt vmcnt(0)" ::: "memory");
        __syncthreads();
#pragma unroll
        for (int kk = 0; kk < 2; kk++) {
            int kp = kpart[kk];
            bf16x8 a[4], bg[4], bu[4];
#pragma unroll
            for (int m = 0; m < 4; m++) a[m] = *(const bf16x8*)(As + aBase + m * 2048 + kp);
#pragma unroll
            for (int n = 0; n < 4; n++) bg[n] = *(const bf16x8*)(As + 16384 + bBase + n * 2048 + kp);
#pragma unroll
            for (int n = 0; n < 4; n++) bu[n] = *(const bf16x8*)(As + 32768 + bBase + n * 2048 + kp);
#pragma unroll
            for (int m = 0; m < 4; m++)
#pragma unroll
                for (int n = 0; n < 4; n++) {
                    accg[m][n] = __builtin_amdgcn_mfma_f32_16x16x32_bf16(a[m], bg[n], accg[m][n], 0, 0, 0);
                    accu[m][n] = __builtin_amdgcn_mfma_f32_16x16x32_bf16(a[m], bu[n], accu[m][n], 0, 0, 0);
                }
        }
    }
    __syncthreads();
    // SiLU(gate)*up -> bf16, stage in LDS [128][128]
    ushort* actl = (ushort*)smem;
#pragma unroll
    for (int m = 0; m < 4; m++)
#pragma unroll
        for (int n = 0; n < 4; n++)
#pragma unroll
            for (int j = 0; j < 4; j++) {
                float gv = accg[m][n][j];
                float uv = accu[m][n][j];
                float av = (gv / (1.f + __expf(-gv))) * uv;
                int row = wr * 64 + m * 16 + lk * 4 + j;
                int col = wc * 64 + n * 16 + lr;
                actl[row * 128 + col] = f2bf(av);
            }
    __syncthreads();
    int crow = tid >> 4, cchunk = tid & 15;
#pragma unroll
    for (int p = 0; p < 8; p++) {
        int row = p * 16 + crow;
        *(uint4*)((char*)act + (size_t)(arow + row) * 1024 + cb * 256 + cchunk * 16) =
            *(const uint4*)((const char*)actl + row * 256 + cchunk * 16);
    }
}

// ---------------- grouped down-GEMM + weighted scatter ----------------
// tile: 128 rows x 128 cols ; BK=64 ; K=512
__global__ __launch_bounds__(256, 2) void k_down(const ushort* __restrict__ act,
                                                 const ushort* __restrict__ wdT,
                                                 float* __restrict__ out,
                                                 const int* __restrict__ tok,
                                                 const float* __restrict__ wgt,
                                                 const int* __restrict__ meta) {
    int rb = blockIdx.y;
    if (rb >= meta[17]) return;
    __shared__ char smem[32768];  // A 16K | B 16K
    int e = meta[32 + rb], rloc = meta[288 + rb], arow = meta[544 + rb];
    int cb = blockIdx.x;
    int tid = threadIdx.x, lane = tid & 63, wave = tid >> 6;

    int srow = tid >> 3;
    int kb = (tid & 7) * 16;
    int swz = kb ^ ((srow & 7) << 4);
    const char* abase = (const char*)act + (size_t)arow * 1024;
    const char* bbase = (const char*)wdT + (size_t)e * 1024 * 1024 + (size_t)cb * 128 * 1024;

    int wr = wave >> 1, wc = wave & 1;
    int lr = lane & 15, lk = lane >> 4;
    int aBase = (wr * 64 + lr) * 128;
    int bBase = (wc * 64 + lr) * 128;
    int kpart[2];
#pragma unroll
    for (int kk = 0; kk < 2; kk++) kpart[kk] = (kk * 64 + lk * 16) ^ ((lr & 7) << 4);

    f32x4 acc[4][4];
#pragma unroll
    for (int m = 0; m < 4; m++)
#pragma unroll
        for (int n = 0; n < 4; n++) acc[m][n] = (f32x4){0.f, 0.f, 0.f, 0.f};

    char* As = smem;
    for (int kt = 0; kt < 8; ++kt) {
        __syncthreads();
        int kB = kt * 128;
#pragma unroll
        for (int i = 0; i < 4; i++)
            gload16(abase + (size_t)(i * 32 + srow) * 1024 + kB + swz, As + i * 4096 + wave * 1024);
#pragma unroll
        for (int i = 0; i < 4; i++)
            gload16(bbase + (size_t)(i * 32 + srow) * 1024 + kB + swz, As + 16384 + i * 4096 + wave * 1024);
        asm volatile("s_waitcnt vmcnt(0)" ::: "memory");
        __syncthreads();
#pragma unroll
        for (int kk = 0; kk < 2; kk++) {
            int kp = kpart[kk];
            bf16x8 a[4], b[4];
#pragma unroll
            for (int m = 0; m < 4; m++) a[m] = *(const bf16x8*)(As + aBase + m * 2048 + kp);
#pragma unroll
            for (int n = 0; n < 4; n++) b[n] = *(const bf16x8*)(As + 16384 + bBase + n * 2048 + kp);
#pragma unroll
            for (int m = 0; m < 4; m++)
#pragma unroll
                for (int n = 0; n < 4; n++)
                    acc[m][n] = __builtin_amdgcn_mfma_f32_16x16x32_bf16(a[m], b[n], acc[m][n], 0, 0, 0);
        }
    }
    const int lb = e * CAP + rloc;
#pragma unroll
    for (int m = 0; m < 4; m++)
#pragma unroll
        for (int j = 0; j < 4; j++) {
            int row = wr * 64 + m * 16 + lk * 4 + j;
            int t = tok[lb + row];
            float w = wgt[lb + row];
            float* orow = out + (size_t)t * 1024 + cb * 128 + wc * 64 + lr;
#pragma unroll
            for (int n = 0; n < 4; n++) atomicAdd(orow + n * 16, acc[m][n][j] * w);
        }
}

extern "C" void kernel_launch(void* const* d_in, const int* in_sizes, int n_in,
                              void* d_out, int out_size, void* d_ws, size_t ws_size,
                              hipStream_t stream) {
    const float* x    = (const float*)d_in[0];
    const float* Wr   = (const float*)d_in[1];
    const float* Wup  = (const float*)d_in[2];
    const float* Wdn  = (const float*)d_in[3];
    const float* Wsup = (const float*)d_in[4];
    const float* Wsdn = (const float*)d_in[5];
    float* out = (float*)d_out;
    float* probs = out + (size_t)T_TOK * HD;

    if (ws_size < WS_NEEDED) return;  // insufficient scratch: fail visibly

    char* ws = (char*)d_ws;
    ushort* xb    = (ushort*)(ws + OFF_XBF);
    ushort* wupT  = (ushort*)(ws + OFF_WUPT);
    ushort* wdT   = (ushort*)(ws + OFF_WDT);
    ushort* act   = (ushort*)(ws + OFF_ACT);
    int2*   eidx  = (int2*)(ws + OFF_EIDX);
    float2* ew    = (float2*)(ws + OFF_EW);
    int*    tok   = (int*)(ws + OFF_TOK);
    float*  wgt   = (float*)(ws + OFF_WGT);
    int*    meta  = (int*)(ws + OFF_META);

    hipMemsetAsync(d_out, 0, (size_t)out_size * 4, stream);
    hipMemsetAsync(meta, 0, 4096, stream);

    k_convert_x<<<(T_TOK * HD) / (256 * 8), 256, 0, stream>>>(x, xb);
    k_transpose_up<<<dim3(32, 32, 17), dim3(32, 8), 0, stream>>>(Wup, Wsup, wupT);
    k_transpose_dn<<<dim3(32, 16, 17), dim3(32, 8), 0, stream>>>(Wdn, Wsdn, wdT);
    k_router<<<T_TOK, 256, 0, stream>>>(x, Wr, probs, eidx, ew);
    k_assign<<<T_TOK / 256, 256, 0, stream>>>(eidx, ew, meta, tok, wgt);
    k_finalize<<<1, 256, 0, stream>>>(meta, tok, wgt);
    k_up<<<dim3(4, MAXRB), 256, 0, stream>>>(xb, wupT, act, tok, meta);
    k_down<<<dim3(8, MAXRB), 256, 0, stream>>>(act, wdT, out, tok, wgt, meta);
}

// Round 3
// 246.371 us; speedup vs baseline: 1.5389x; 1.5389x over previous
//
#include <hip/hip_runtime.h>
#include <stdint.h>

#define T_TOK 8192
#define HD 1024
#define NE 16
#define NET 17
#define FD 512
#define CAP 8320
#define MAXRB 208

typedef unsigned int uint;
typedef unsigned short ushort;
typedef __attribute__((ext_vector_type(8))) __bf16 bf16x8;
typedef __attribute__((ext_vector_type(4))) float f32x4;
typedef __attribute__((ext_vector_type(8))) ushort u16x8;

// ws layout (bytes)
#define OFF_XBF   0ull           // 16 MB  (dead after k_up -> reused as ybuf)
#define OFF_WUPT  16777216ull    // 35.6 MB (dead after k_up -> reused as ybuf)
#define OFF_WDT   52428800ull
#define OFF_ACT   70254592ull
#define OFF_EIDX  97517568ull    // k_assign rewrites as inv_a (e0,p0)
#define OFF_EW    97583104ull    // k_assign rewrites as inv_b (e1,p1)
#define OFF_TOK   97648640ull
#define OFF_WGT   98214400ull
#define OFF_META  98780160ull
#define WS_NEEDED (OFF_META + 4096ull)
// ybuf: COMPACT (unpadded) rows: exactly 16384 expert rows + 8192 shared
// = 24576 rows x 1024 x 2B = 50,331,648 B < OFF_WDT (52,428,800). Deterministic
// bound -- pad rows are masked off at store time, never written.

__device__ __forceinline__ ushort f2bf(float f) {
    uint u = __float_as_uint(f);
    u += 0x7FFFu + ((u >> 16) & 1u);
    return (ushort)(u >> 16);
}
__device__ __forceinline__ float bf2f(ushort u) {
    return __uint_as_float(((uint)u) << 16);
}

__device__ __forceinline__ void gload16(const void* g, void* l) {
    __builtin_amdgcn_global_load_lds(
        (const __attribute__((address_space(1))) void*)g,
        (__attribute__((address_space(3))) void*)l, 16, 0, 0);
}

// ---------------- conversions ----------------
__global__ void k_convert_x(const float* __restrict__ x, ushort* __restrict__ xb) {
    int i = (blockIdx.x * 256 + threadIdx.x) * 8;
    float4 a = *(const float4*)(x + i);
    float4 b = *(const float4*)(x + i + 4);
    u16x8 v;
    v[0] = f2bf(a.x); v[1] = f2bf(a.y); v[2] = f2bf(a.z); v[3] = f2bf(a.w);
    v[4] = f2bf(b.x); v[5] = f2bf(b.y); v[6] = f2bf(b.z); v[7] = f2bf(b.w);
    *(u16x8*)(xb + i) = v;
}

// W_up [E][H][2F] fp32 (+ shared [H][2F]) -> wupT [17][2F][H] bf16
__global__ void k_transpose_up(const float* __restrict__ Wup,
                               const float* __restrict__ Wsup,
                               ushort* __restrict__ dst) {
    int e = blockIdx.z;
    const float* src = (e < 16) ? (Wup + (size_t)e * HD * (2 * FD)) : Wsup;
    int h0 = blockIdx.y * 32, n0 = blockIdx.x * 32;
    __shared__ float tile[32][33];
    int tx = threadIdx.x, ty = threadIdx.y;
#pragma unroll
    for (int i = 0; i < 4; i++) {
        int r = ty + i * 8;
        tile[r][tx] = src[(size_t)(h0 + r) * (2 * FD) + n0 + tx];
    }
    __syncthreads();
#pragma unroll
    for (int i = 0; i < 4; i++) {
        int r = ty + i * 8;
        dst[(size_t)e * 1024 * 1024 + (size_t)(n0 + r) * 1024 + h0 + tx] = f2bf(tile[tx][r]);
    }
}

// W_down [E][F][H] fp32 (+ shared [F][H]) -> wdT [17][H][F] bf16
__global__ void k_transpose_dn(const float* __restrict__ Wdn,
                               const float* __restrict__ Wsdn,
                               ushort* __restrict__ dst) {
    int e = blockIdx.z;
    const float* src = (e < 16) ? (Wdn + (size_t)e * FD * HD) : Wsdn;
    int f0 = blockIdx.y * 32, h0 = blockIdx.x * 32;
    __shared__ float tile[32][33];
    int tx = threadIdx.x, ty = threadIdx.y;
#pragma unroll
    for (int i = 0; i < 4; i++) {
        int r = ty + i * 8;
        tile[r][tx] = src[(size_t)(f0 + r) * HD + h0 + tx];
    }
    __syncthreads();
#pragma unroll
    for (int i = 0; i < 4; i++) {
        int r = ty + i * 8;
        dst[(size_t)e * 1024 * 512 + (size_t)(h0 + r) * 512 + f0 + tx] = f2bf(tile[tx][r]);
    }
}

// ---------------- router ----------------
__global__ __launch_bounds__(256) void k_router(const float* __restrict__ x,
                                                const float* __restrict__ Wr,
                                                float* __restrict__ probs,
                                                int2* __restrict__ eidx,
                                                float2* __restrict__ ew) {
    int t = blockIdx.x;
    __shared__ float xs[HD];
    __shared__ float part[256];
    __shared__ float pl[NE];
    int tid = threadIdx.x;
    *(float4*)(xs + tid * 4) = *(const float4*)(x + (size_t)t * HD + tid * 4);
    __syncthreads();
    int e = tid & 15, g = tid >> 4;
    float s = 0.f;
#pragma unroll 8
    for (int h = g * 64; h < g * 64 + 64; ++h) s += xs[h] * Wr[h * NE + e];
    part[tid] = s;
    __syncthreads();
    if (tid < NE) {
        float l = 0.f;
#pragma unroll
        for (int gg = 0; gg < 16; ++gg) l += part[gg * 16 + tid];
        pl[tid] = l;
    }
    __syncthreads();
    if (tid == 0) {
        float mx = pl[0];
#pragma unroll
        for (int i = 1; i < NE; ++i) mx = fmaxf(mx, pl[i]);
        float p[NE];
        float sum = 0.f;
#pragma unroll
        for (int i = 0; i < NE; ++i) { p[i] = __expf(pl[i] - mx); sum += p[i]; }
        float inv = 1.f / sum;
        float m1 = -1.f; int i1 = 0;
#pragma unroll
        for (int i = 0; i < NE; ++i) {
            p[i] *= inv;
            probs[(size_t)t * NE + i] = p[i];
            if (p[i] > m1) { m1 = p[i]; i1 = i; }
        }
        float m2 = -1.f; int i2 = 0;
#pragma unroll
        for (int i = 0; i < NE; ++i) if (i != i1 && p[i] > m2) { m2 = p[i]; i2 = i; }
        float inv2 = 1.f / (m1 + m2 + 1e-9f);
        eidx[t] = make_int2(i1, i2);
        ew[t] = make_float2(m1 * inv2, m2 * inv2);
    }
}

// ---------------- bucketing ----------------
// After reading its own eidx/ew, each thread rewrites those slots as the
// inverse map: inv_a[t]=(e0,p0), inv_b[t]=(e1,p1) for k_combine.
__global__ void k_assign(int2* __restrict__ eidx, float2* __restrict__ ew,
                         int* __restrict__ meta, int* __restrict__ tok,
                         float* __restrict__ wgt) {
    int t = blockIdx.x * 256 + threadIdx.x;
    int2 e = eidx[t];
    float2 w = ew[t];
    int p0 = atomicAdd(&meta[e.x], 1);
    tok[e.x * CAP + p0] = t; wgt[e.x * CAP + p0] = w.x;
    int p1 = atomicAdd(&meta[e.y], 1);
    tok[e.y * CAP + p1] = t; wgt[e.y * CAP + p1] = w.y;
    tok[16 * CAP + t] = t; wgt[16 * CAP + t] = 1.f;   // shared expert: identity list
    eidx[t] = make_int2(e.x, p0);                     // inv_a
    ((int2*)ew)[t] = make_int2(e.y, p1);              // inv_b
    if (t == 0) meta[16] = T_TOK;
}

// meta: [0..16]=cnt, [17]=nRB, [32..]=rbE, [288..]=rbLoc, [544..]=rbActRow,
//       [760..776]=ybase per expert (UNPADDED cumulative; shared at [776])
__global__ void k_finalize(int* __restrict__ meta, int* __restrict__ tok,
                           float* __restrict__ wgt) {
    __shared__ int sN[NET], sPad[NET];
    int tid = threadIdx.x;
    if (tid == 0) {
        int idx = 0, aoff = 0, yoff = 0;
        for (int e = 0; e < NET; e++) {
            int n = meta[e];
            int padded = (n + 127) & ~127;
            sN[e] = n; sPad[e] = padded;
            meta[760 + e] = yoff;
            for (int i = 0; i < padded; i += 128) {
                meta[32 + idx] = e; meta[288 + idx] = i; meta[544 + idx] = aoff + i; idx++;
            }
            aoff += padded; yoff += n;
        }
        meta[17] = idx;
    }
    __syncthreads();
    for (int e = 0; e < NET; e++)
        for (int i = sN[e] + tid; i < sPad[e]; i += 256) {
            tok[e * CAP + i] = 0; wgt[e * CAP + i] = 0.f;
        }
}

// ---------------- grouped up-GEMM + SiLU (gate,up paired) ----------------
// tile: 128 rows x (128 gate + 128 up cols) ; BK=64 ; K=1024 ; 4 waves of 64x64(+64x64)
__global__ __launch_bounds__(256, 2) void k_up(const ushort* __restrict__ xb,
                                               const ushort* __restrict__ wupT,
                                               ushort* __restrict__ act,
                                               const int* __restrict__ tok,
                                               const int* __restrict__ meta) {
    int rb = blockIdx.y;
    if (rb >= meta[17]) return;
    __shared__ char smem[49152];  // A 16K | Bg 16K | Bu 16K ; epilogue reuses 32K
    int e = meta[32 + rb], rloc = meta[288 + rb], arow = meta[544 + rb];
    int cb = blockIdx.x;
    int tid = threadIdx.x, lane = tid & 63, wave = tid >> 6;

    // staging: thread stages LDS bytes [tid*16, +16) of each 4KB issue
    int srow = tid >> 3;              // row within 32-row issue
    int kb = (tid & 7) * 16;
    int swz = kb ^ ((srow & 7) << 4);
    const int listBase = e * CAP + rloc;
    int tokr[4];
#pragma unroll
    for (int i = 0; i < 4; i++) tokr[i] = tok[listBase + i * 32 + srow];
    const char* xbase = (const char*)xb;
    const char* wb = (const char*)wupT + (size_t)e * 1024 * 2048;
    int ng = cb * 128 + srow;

    int wr = wave >> 1, wc = wave & 1;
    int lr = lane & 15, lk = lane >> 4;
    int aBase = (wr * 64 + lr) * 128;
    int bBase = (wc * 64 + lr) * 128;
    int kpart[2];
#pragma unroll
    for (int kk = 0; kk < 2; kk++) kpart[kk] = (kk * 64 + lk * 16) ^ ((lr & 7) << 4);

    f32x4 accg[4][4], accu[4][4];
#pragma unroll
    for (int m = 0; m < 4; m++)
#pragma unroll
        for (int n = 0; n < 4; n++) {
            accg[m][n] = (f32x4){0.f, 0.f, 0.f, 0.f};
            accu[m][n] = (f32x4){0.f, 0.f, 0.f, 0.f};
        }

    char* As = smem;
    for (int kt = 0; kt < 16; ++kt) {
        __syncthreads();
        int kB = kt * 128;
#pragma unroll
        for (int i = 0; i < 4; i++)
            gload16(xbase + (size_t)tokr[i] * 2048 + kB + swz, As + i * 4096 + wave * 1024);
#pragma unroll
        for (int i = 0; i < 4; i++)
            gload16(wb + (size_t)(ng + i * 32) * 2048 + kB + swz, As + 16384 + i * 4096 + wave * 1024);
#pragma unroll
        for (int i = 0; i < 4; i++)
            gload16(wb + (size_t)(ng + 512 + i * 32) * 2048 + kB + swz, As + 32768 + i * 4096 + wave * 1024);
        asm volatile("s_waitcnt vmcnt(0)" ::: "memory");
        __syncthreads();
#pragma unroll
        for (int kk = 0; kk < 2; kk++) {
            int kp = kpart[kk];
            bf16x8 a[4], bg[4], bu[4];
#pragma unroll
            for (int m = 0; m < 4; m++) a[m] = *(const bf16x8*)(As + aBase + m * 2048 + kp);
#pragma unroll
            for (int n = 0; n < 4; n++) bg[n] = *(const bf16x8*)(As + 16384 + bBase + n * 2048 + kp);
#pragma unroll
            for (int n = 0; n < 4; n++) bu[n] = *(const bf16x8*)(As + 32768 + bBase + n * 2048 + kp);
#pragma unroll
            for (int m = 0; m < 4; m++)
#pragma unroll
                for (int n = 0; n < 4; n++) {
                    accg[m][n] = __builtin_amdgcn_mfma_f32_16x16x32_bf16(a[m], bg[n], accg[m][n], 0, 0, 0);
                    accu[m][n] = __builtin_amdgcn_mfma_f32_16x16x32_bf16(a[m], bu[n], accu[m][n], 0, 0, 0);
                }
        }
    }
    __syncthreads();
    // SiLU(gate)*up -> bf16, stage in LDS [128][128]
    ushort* actl = (ushort*)smem;
#pragma unroll
    for (int m = 0; m < 4; m++)
#pragma unroll
        for (int n = 0; n < 4; n++)
#pragma unroll
            for (int j = 0; j < 4; j++) {
                float gv = accg[m][n][j];
                float uv = accu[m][n][j];
                float av = (gv / (1.f + __expf(-gv))) * uv;
                int row = wr * 64 + m * 16 + lk * 4 + j;
                int col = wc * 64 + n * 16 + lr;
                actl[row * 128 + col] = f2bf(av);
            }
    __syncthreads();
    int crow = tid >> 4, cchunk = tid & 15;
#pragma unroll
    for (int p = 0; p < 8; p++) {
        int row = p * 16 + crow;
        *(uint4*)((char*)act + (size_t)(arow + row) * 1024 + cb * 256 + cchunk * 16) =
            *(const uint4*)((const char*)actl + row * 256 + cchunk * 16);
    }
}

// ---------------- grouped down-GEMM + scaled bf16 store (compact rows) ----------------
// tile: 128 rows x 128 cols ; BK=64 ; K=512 ; writes w*y as bf16 to ybuf[ybase+pos]
__global__ __launch_bounds__(256, 2) void k_down(const ushort* __restrict__ act,
                                                 const ushort* __restrict__ wdT,
                                                 ushort* __restrict__ ybuf,
                                                 const int* __restrict__ tok,
                                                 const float* __restrict__ wgt,
                                                 const int* __restrict__ meta) {
    int rb = blockIdx.y;
    if (rb >= meta[17]) return;
    __shared__ char smem[32768];  // A 16K | B 16K ; epilogue reuses all 32K
    int e = meta[32 + rb], rloc = meta[288 + rb], arow = meta[544 + rb];
    int cb = blockIdx.x;
    int tid = threadIdx.x, lane = tid & 63, wave = tid >> 6;

    int srow = tid >> 3;
    int kb = (tid & 7) * 16;
    int swz = kb ^ ((srow & 7) << 4);
    const char* abase = (const char*)act + (size_t)arow * 1024;
    const char* bbase = (const char*)wdT + (size_t)e * 1024 * 1024 + (size_t)cb * 128 * 1024;

    int wr = wave >> 1, wc = wave & 1;
    int lr = lane & 15, lk = lane >> 4;
    int aBase = (wr * 64 + lr) * 128;
    int bBase = (wc * 64 + lr) * 128;
    int kpart[2];
#pragma unroll
    for (int kk = 0; kk < 2; kk++) kpart[kk] = (kk * 64 + lk * 16) ^ ((lr & 7) << 4);

    f32x4 acc[4][4];
#pragma unroll
    for (int m = 0; m < 4; m++)
#pragma unroll
        for (int n = 0; n < 4; n++) acc[m][n] = (f32x4){0.f, 0.f, 0.f, 0.f};

    char* As = smem;
    for (int kt = 0; kt < 8; ++kt) {
        __syncthreads();
        int kB = kt * 128;
#pragma unroll
        for (int i = 0; i < 4; i++)
            gload16(abase + (size_t)(i * 32 + srow) * 1024 + kB + swz, As + i * 4096 + wave * 1024);
#pragma unroll
        for (int i = 0; i < 4; i++)
            gload16(bbase + (size_t)(i * 32 + srow) * 1024 + kB + swz, As + 16384 + i * 4096 + wave * 1024);
        asm volatile("s_waitcnt vmcnt(0)" ::: "memory");
        __syncthreads();
#pragma unroll
        for (int kk = 0; kk < 2; kk++) {
            int kp = kpart[kk];
            bf16x8 a[4], b[4];
#pragma unroll
            for (int m = 0; m < 4; m++) a[m] = *(const bf16x8*)(As + aBase + m * 2048 + kp);
#pragma unroll
            for (int n = 0; n < 4; n++) b[n] = *(const bf16x8*)(As + 16384 + bBase + n * 2048 + kp);
#pragma unroll
            for (int m = 0; m < 4; m++)
#pragma unroll
                for (int n = 0; n < 4; n++)
                    acc[m][n] = __builtin_amdgcn_mfma_f32_16x16x32_bf16(a[m], b[n], acc[m][n], 0, 0, 0);
        }
    }
    __syncthreads();
    // scale by router weight, stage bf16 tile in LDS [128][128]
    const int lb = e * CAP + rloc;
    const int ne = meta[e];
    const int ybase = meta[760 + e];
    ushort* yl = (ushort*)smem;
#pragma unroll
    for (int m = 0; m < 4; m++)
#pragma unroll
        for (int j = 0; j < 4; j++) {
            int row = wr * 64 + m * 16 + lk * 4 + j;
            float w = wgt[lb + row];
#pragma unroll
            for (int n = 0; n < 4; n++) {
                int col = wc * 64 + n * 16 + lr;
                yl[row * 128 + col] = f2bf(acc[m][n][j] * w);
            }
        }
    __syncthreads();
    int crow = tid >> 4, cchunk = tid & 15;
#pragma unroll
    for (int p = 0; p < 8; p++) {
        int row = p * 16 + crow;
        if (rloc + row < ne) {   // mask pad rows -> compact ybuf stays in bounds
            *(uint4*)((char*)ybuf + (size_t)(ybase + rloc + row) * 2048 + cb * 256 + cchunk * 16) =
                *(const uint4*)((const char*)yl + row * 256 + cchunk * 16);
        }
    }
}

// ---------------- per-token combine: out = y[e0 row] + y[e1 row] + y[shared row] ----------------
__global__ __launch_bounds__(256) void k_combine(const ushort* __restrict__ y,
                                                 const int2* __restrict__ ia,
                                                 const int2* __restrict__ ib,
                                                 const int* __restrict__ meta,
                                                 float* __restrict__ out) {
    int t = blockIdx.x;
    int2 a = ia[t], b = ib[t];
    int r0 = (meta[760 + a.x] + a.y) << 10;
    int r1 = (meta[760 + b.x] + b.y) << 10;
    int rs = (meta[776] + t) << 10;
    int c = threadIdx.x << 2;
    ushort4 va = *(const ushort4*)(y + r0 + c);
    ushort4 vb = *(const ushort4*)(y + r1 + c);
    ushort4 vs = *(const ushort4*)(y + rs + c);
    float4 o;
    o.x = bf2f(va.x) + bf2f(vb.x) + bf2f(vs.x);
    o.y = bf2f(va.y) + bf2f(vb.y) + bf2f(vs.y);
    o.z = bf2f(va.z) + bf2f(vb.z) + bf2f(vs.z);
    o.w = bf2f(va.w) + bf2f(vb.w) + bf2f(vs.w);
    *(float4*)(out + ((size_t)t << 10) + c) = o;
}

extern "C" void kernel_launch(void* const* d_in, const int* in_sizes, int n_in,
                              void* d_out, int out_size, void* d_ws, size_t ws_size,
                              hipStream_t stream) {
    const float* x    = (const float*)d_in[0];
    const float* Wr   = (const float*)d_in[1];
    const float* Wup  = (const float*)d_in[2];
    const float* Wdn  = (const float*)d_in[3];
    const float* Wsup = (const float*)d_in[4];
    const float* Wsdn = (const float*)d_in[5];
    float* out = (float*)d_out;
    float* probs = out + (size_t)T_TOK * HD;

    if (ws_size < WS_NEEDED) return;  // insufficient scratch: fail visibly

    char* ws = (char*)d_ws;
    ushort* xb    = (ushort*)(ws + OFF_XBF);
    ushort* wupT  = (ushort*)(ws + OFF_WUPT);
    ushort* wdT   = (ushort*)(ws + OFF_WDT);
    ushort* act   = (ushort*)(ws + OFF_ACT);
    int2*   eidx  = (int2*)(ws + OFF_EIDX);
    float2* ew    = (float2*)(ws + OFF_EW);
    int*    tok   = (int*)(ws + OFF_TOK);
    float*  wgt   = (float*)(ws + OFF_WGT);
    int*    meta  = (int*)(ws + OFF_META);
    ushort* ybuf  = (ushort*)(ws + OFF_XBF);   // aliases xb+wupT (dead after k_up); max 50.33 MB

    hipMemsetAsync(meta, 0, 4096, stream);

    k_convert_x<<<(T_TOK * HD) / (256 * 8), 256, 0, stream>>>(x, xb);
    k_transpose_up<<<dim3(32, 32, 17), dim3(32, 8), 0, stream>>>(Wup, Wsup, wupT);
    k_transpose_dn<<<dim3(32, 16, 17), dim3(32, 8), 0, stream>>>(Wdn, Wsdn, wdT);
    k_router<<<T_TOK, 256, 0, stream>>>(x, Wr, probs, eidx, ew);
    k_assign<<<T_TOK / 256, 256, 0, stream>>>(eidx, ew, meta, tok, wgt);
    k_finalize<<<1, 256, 0, stream>>>(meta, tok, wgt);
    k_up<<<dim3(4, MAXRB), 256, 0, stream>>>(xb, wupT, act, tok, meta);
    k_down<<<dim3(8, MAXRB), 256, 0, stream>>>(act, wdT, ybuf, tok, wgt, meta);
    k_combine<<<T_TOK, 256, 0, stream>>>(ybuf, eidx, (const int2*)ew, meta, out);
}